// Round 1
// baseline (1200.186 us; speedup 1.0000x reference)
//
#include <hip/hip_runtime.h>

#define N_TOT   65536
#define K_EMB   1024
#define D_EMB   256
#define HW      1024
#define CHW     (D_EMB * HW)          // 262144

// output offsets (float elements), reference tuple order
#define O_DIST  0                      // [65536,1024]
#define O_Q     67108864               // [64,256,32,32]
#define O_LOSS  83886080               // scalar
#define O_ENC   83886081               // [65536,1024]
#define O_IDX   150994945              // [65536,1]
#define O_PPL   151060481              // scalar

// workspace offsets (bytes)
#define WS_CNT   0                     // int[1024]
#define WS_LOSSP 4096                  // double[256]
#define WS_XX    6144                  // float[65536]
#define WS_WW    268288                // float[1024]
#define WS_IDX   272384                // int[65536]  -> ends 534528 B

// ---------------- row norms ----------------
__global__ __launch_bounds__(256) void k_xx(const float* __restrict__ in,
                                            float* __restrict__ xx) {
  int n = blockIdx.x * 256 + threadIdx.x;
  int b = n >> 10, hw = n & 1023;
  const float* p = in + (size_t)b * CHW + hw;
  float s = 0.f;
  #pragma unroll 8
  for (int d = 0; d < D_EMB; ++d) { float v = p[(size_t)d * HW]; s += v * v; }
  xx[n] = s;
}

__global__ __launch_bounds__(256) void k_ww(const float* __restrict__ w,
                                            float* __restrict__ ww) {
  int k = blockIdx.x * 256 + threadIdx.x;
  const float* p = w + (size_t)k * D_EMB;
  float s = 0.f;
  #pragma unroll 8
  for (int d = 0; d < D_EMB; ++d) { float v = p[d]; s += v * v; }
  ww[k] = s;
}

// ---------------- fp32 GEMM + distances + argmin ----------------
// BN=64 rows(n) per block, loops all K in chunks of 64, D in chunks of 32.
// 256 threads: tx=k-quad (16), ty=n-quad (16); 4x4 accumulators each.
__global__ __launch_bounds__(256) void k_gemm(const float* __restrict__ in,
                                              const float* __restrict__ w,
                                              const float* __restrict__ xx,
                                              const float* __restrict__ ww,
                                              float* __restrict__ dist,
                                              int* __restrict__ aidx) {
  __shared__ __align__(16) float xs[32][68];   // [d][n] transposed, pad 68
  __shared__ __align__(16) float wsh[32][68];  // [d][k] transposed, pad 68
  __shared__ float rbest[64][16];
  __shared__ int   ridx[64][16];

  const int tid = threadIdx.x;
  const int tx = tid & 15, ty = tid >> 4;
  const int n0 = blockIdx.x * 64;
  const int b = n0 >> 10, hw0 = n0 & 1023;
  const float* xbase = in + (size_t)b * CHW + hw0;

  float best[4]; int bestk[4];
  #pragma unroll
  for (int i = 0; i < 4; ++i) { best[i] = 3.4e38f; bestk[i] = 0; }

  const int xr = tid >> 6;        // 0..3 (d sub-row for x staging)
  const int xc = tid & 63;        // n
  const int wk = tid >> 3;        // 0..31 (k for w staging)
  const int wd = (tid & 7) * 4;   // d quad

  for (int k0 = 0; k0 < K_EMB; k0 += 64) {
    float acc[4][4];
    #pragma unroll
    for (int i = 0; i < 4; ++i)
      #pragma unroll
      for (int j = 0; j < 4; ++j) acc[i][j] = 0.f;

    for (int d0 = 0; d0 < D_EMB; d0 += 32) {
      __syncthreads();  // LDS reuse guard
      #pragma unroll
      for (int it = 0; it < 8; ++it) {
        int dl = it * 4 + xr;
        xs[dl][xc] = xbase[(size_t)(d0 + dl) * HW + xc];
      }
      #pragma unroll
      for (int p = 0; p < 2; ++p) {
        int kl = p * 32 + wk;
        float4 v = *(const float4*)&w[(size_t)(k0 + kl) * D_EMB + d0 + wd];
        wsh[wd + 0][kl] = v.x; wsh[wd + 1][kl] = v.y;
        wsh[wd + 2][kl] = v.z; wsh[wd + 3][kl] = v.w;
      }
      __syncthreads();
      #pragma unroll
      for (int dd = 0; dd < 32; ++dd) {
        float4 xv = *(const float4*)&xs[dd][ty * 4];
        float4 wv = *(const float4*)&wsh[dd][tx * 4];
        acc[0][0] += xv.x * wv.x; acc[0][1] += xv.x * wv.y;
        acc[0][2] += xv.x * wv.z; acc[0][3] += xv.x * wv.w;
        acc[1][0] += xv.y * wv.x; acc[1][1] += xv.y * wv.y;
        acc[1][2] += xv.y * wv.z; acc[1][3] += xv.y * wv.w;
        acc[2][0] += xv.z * wv.x; acc[2][1] += xv.z * wv.y;
        acc[2][2] += xv.z * wv.z; acc[2][3] += xv.z * wv.w;
        acc[3][0] += xv.w * wv.x; acc[3][1] += xv.w * wv.y;
        acc[3][2] += xv.w * wv.z; acc[3][3] += xv.w * wv.w;
      }
    }
    // distances for this k-chunk: d = xx - 2*dot + ww  (same fl sequence as np)
    float4 wwv = *(const float4*)&ww[k0 + tx * 4];
    #pragma unroll
    for (int i = 0; i < 4; ++i) {
      int nl = ty * 4 + i;
      float xxv = xx[n0 + nl];
      float4 o;
      o.x = xxv - 2.f * acc[i][0] + wwv.x;
      o.y = xxv - 2.f * acc[i][1] + wwv.y;
      o.z = xxv - 2.f * acc[i][2] + wwv.z;
      o.w = xxv - 2.f * acc[i][3] + wwv.w;
      *(float4*)&dist[(size_t)(n0 + nl) * K_EMB + k0 + tx * 4] = o;
      float dv[4] = {o.x, o.y, o.z, o.w};
      #pragma unroll
      for (int j = 0; j < 4; ++j) {
        if (dv[j] < best[i]) { best[i] = dv[j]; bestk[i] = k0 + tx * 4 + j; }
      }
    }
  }
  // cross-thread argmin reduce (16 tx per row), ties -> lowest k
  #pragma unroll
  for (int i = 0; i < 4; ++i) {
    rbest[ty * 4 + i][tx] = best[i];
    ridx[ty * 4 + i][tx] = bestk[i];
  }
  __syncthreads();
  if (tid < 64) {
    float bb = rbest[tid][0]; int bk = ridx[tid][0];
    #pragma unroll
    for (int t = 1; t < 16; ++t) {
      float v = rbest[tid][t]; int kk = ridx[tid][t];
      if (v < bb || (v == bb && kk < bk)) { bb = v; bk = kk; }
    }
    aidx[n0 + tid] = bk;
  }
}

// ---------------- epilogue: quantized, one-hot, indices, loss, histogram ----
__global__ __launch_bounds__(256) void k_epi(const float* __restrict__ in,
                                             const float* __restrict__ w,
                                             const int* __restrict__ aidx,
                                             float* __restrict__ outq,
                                             float* __restrict__ enc,
                                             float* __restrict__ idxf,
                                             int* __restrict__ cnt,
                                             double* __restrict__ lossp) {
  __shared__ double sred[256];
  int tid = threadIdx.x;
  int n = blockIdx.x * 256 + tid;
  int b = n >> 10, hw = n & 1023;
  int idx = aidx[n];
  const float* xp = in + (size_t)b * CHW + hw;
  float* qp = outq + (size_t)b * CHW + hw;
  const float* wrow = w + (size_t)idx * D_EMB;
  double ls = 0.0;
  #pragma unroll 4
  for (int d = 0; d < D_EMB; ++d) {
    float xv = xp[(size_t)d * HW];
    float q = wrow[d];
    float t = q - xv;                 // fl(q - x), same as np
    qp[(size_t)d * HW] = xv + t;      // fl(x + t), bit-identical to np STE
    float sq = t * t;
    ls += (double)sq;
  }
  enc[(size_t)n * K_EMB + idx] = 1.0f;
  idxf[n] = (float)idx;
  atomicAdd(&cnt[idx], 1);
  sred[tid] = ls; __syncthreads();
  for (int s = 128; s > 0; s >>= 1) {
    if (tid < s) sred[tid] += sred[tid + s];
    __syncthreads();
  }
  if (tid == 0) lossp[blockIdx.x] = sred[0];
}

// ---------------- finalize scalars ----------------
__global__ __launch_bounds__(256) void k_final(const double* __restrict__ lossp,
                                               const int* __restrict__ cnt,
                                               float* __restrict__ out_loss,
                                               float* __restrict__ out_ppl) {
  __shared__ double sred[256];
  int t = threadIdx.x;
  sred[t] = lossp[t];
  __syncthreads();
  for (int s = 128; s > 0; s >>= 1) {
    if (t < s) sred[t] += sred[t + s];
    __syncthreads();
  }
  if (t == 0) *out_loss = (float)(1.25 * (sred[0] / 16777216.0));
  __syncthreads();
  double es = 0.0;
  for (int k = t; k < K_EMB; k += 256) {
    float p = (float)cnt[k] * (1.0f / 65536.0f);
    float term = p * logf(p + 1e-10f);
    es += (double)term;
  }
  sred[t] = es;
  __syncthreads();
  for (int s = 128; s > 0; s >>= 1) {
    if (t < s) sred[t] += sred[t + s];
    __syncthreads();
  }
  if (t == 0) *out_ppl = expf((float)(-sred[0]));
}

extern "C" void kernel_launch(void* const* d_in, const int* in_sizes, int n_in,
                              void* d_out, int out_size, void* d_ws, size_t ws_size,
                              hipStream_t stream) {
  const float* in = (const float*)d_in[0];
  const float* w  = (const float*)d_in[1];
  float* out = (float*)d_out;
  char* ws = (char*)d_ws;

  int*    cnt   = (int*)(ws + WS_CNT);
  double* lossp = (double*)(ws + WS_LOSSP);
  float*  xx    = (float*)(ws + WS_XX);
  float*  wwp   = (float*)(ws + WS_WW);
  int*    aidx  = (int*)(ws + WS_IDX);

  // zero histogram + one-hot encodings region (ws/out are poisoned 0xAA)
  hipMemsetAsync(cnt, 0, 4096, stream);
  hipMemsetAsync(out + O_ENC, 0, (size_t)67108864 * 4, stream);

  k_xx  <<<256, 256, 0, stream>>>(in, xx);
  k_ww  <<<4,   256, 0, stream>>>(w, wwp);
  k_gemm<<<1024, 256, 0, stream>>>(in, w, xx, wwp, out + O_DIST, aidx);
  k_epi <<<256, 256, 0, stream>>>(in, w, aidx, out + O_Q, out + O_ENC,
                                  out + O_IDX, cnt, lossp);
  k_final<<<1, 256, 0, stream>>>(lossp, cnt, out + O_LOSS, out + O_PPL);
}

// Round 9
// 1026.950 us; speedup vs baseline: 1.1687x; 1.1687x over previous
//
#include <hip/hip_runtime.h>
#include <hip/hip_fp16.h>

#define N_TOT   65536
#define K_EMB   1024
#define D_EMB   256
#define HW      1024
#define CHW     (D_EMB * HW)

// output offsets (float elements), reference tuple order
#define O_DIST  0
#define O_Q     67108864
#define O_LOSS  83886080
#define O_ENC   83886081
#define O_IDX   150994945
#define O_PPL   151060481

// workspace offsets (bytes)
#define WS_CNT   0                     // int[1024]
#define WS_LOSSP 4096                  // double[1024] -> 12288
#define WS_XX    12288                 // float[65536] -> 274432
#define WS_WW    274432                // float[1024]  -> 278528
#define WS_AIDX  278528                // int[65536]   -> 534528

#define CAP     15
#define MARGIN  3.0e-4f

typedef float  f32x4  __attribute__((ext_vector_type(4)));
typedef short  short8 __attribute__((ext_vector_type(8)));
typedef unsigned short ushort8 __attribute__((ext_vector_type(8)));
typedef f32x4 __attribute__((aligned(4))) f32x4u;

static __device__ __forceinline__ void gload16(const void* g, void* l) {
  __builtin_amdgcn_global_load_lds(
      (const __attribute__((address_space(1))) unsigned int*)g,
      (__attribute__((address_space(3))) unsigned int*)l, 16, 0, 0);
}

// ---- prep x: f16 convert + numpy-pairwise-exact ||x||^2 -------------------
// np.sum(flat*flat,1): n=256 -> pw(0,128)+pw(128,256); each 128: 8-acc
// unrolled loop then ((r0+r1)+(r2+r3))+((r4+r5)+(r6+r7)). Replicated exactly.
__global__ __launch_bounds__(256) void k_prep_x(const float* __restrict__ in,
                                                unsigned short* __restrict__ x2,
                                                float* __restrict__ xx) {
  int n = blockIdx.x * 256 + threadIdx.x;
  int b = n >> 10, hw = n & 1023;
  const float* p = in + (size_t)b * CHW + hw;
  float hsum[2];
  #pragma unroll
  for (int half = 0; half < 2; ++half) {
    float r[8];
    for (int i = 0; i < 128; i += 8) {
      ushort8 hv;
      #pragma unroll
      for (int j = 0; j < 8; ++j) {
        int d = half * 128 + i + j;
        float v = p[(size_t)d * HW];
        float sq = v * v;
        asm volatile("" : "+v"(sq));      // block fma-contraction: np rounds v*v first
        if (i == 0) r[j] = sq; else r[j] += sq;
        hv[j] = __half_as_ushort(__float2half_rn(v));
      }
      *(ushort8*)&x2[(size_t)n * 256 + half * 128 + i] = hv;
    }
    hsum[half] = ((r[0] + r[1]) + (r[2] + r[3])) + ((r[4] + r[5]) + (r[6] + r[7]));
  }
  xx[n] = hsum[0] + hsum[1];
}

// ---- prep w: f16(1024*w) + numpy-pairwise-exact ||w||^2 -------------------
__global__ __launch_bounds__(256) void k_prep_w(const float* __restrict__ w,
                                                unsigned short* __restrict__ w2,
                                                float* __restrict__ ww) {
  int k = blockIdx.x * 256 + threadIdx.x;
  const float* p = w + (size_t)k * D_EMB;
  float hsum[2];
  #pragma unroll
  for (int half = 0; half < 2; ++half) {
    float r[8];
    for (int i = 0; i < 128; i += 8) {
      ushort8 hv;
      #pragma unroll
      for (int j = 0; j < 8; ++j) {
        float v = p[half * 128 + i + j];
        float sq = v * v;
        asm volatile("" : "+v"(sq));
        if (i == 0) r[j] = sq; else r[j] += sq;
        hv[j] = __half_as_ushort(__float2half_rn(v * 1024.f));  // exact scale
      }
      *(ushort8*)&w2[(size_t)k * 256 + half * 128 + i] = hv;
    }
    hsum[half] = ((r[0] + r[1]) + (r[2] + r[3])) + ((r[4] + r[5]) + (r[6] + r[7]));
  }
  ww[k] = hsum[0] + hsum[1];
}

// ---- coarse MFMA GEMM: dist output + per-row candidate shortlist ----------
// 512 blocks x 512 thr; block owns 128 rows x ALL 1024 cols. BK=32 dbuf.
// acc = sum xh*(1024*w)h ; dd_c = (xx - acc/512) + ww  (error ~1e-5 << MARGIN)
__global__ __launch_bounds__(512) void k_coarse(const unsigned short* __restrict__ x2,
                                                const unsigned short* __restrict__ w2,
                                                const float* __restrict__ xx,
                                                const float* __restrict__ ww,
                                                float* __restrict__ dist,
                                                unsigned short* __restrict__ cand) {
  __shared__ __align__(16) short As[2][4096];   // [128][32] f16 (64 B rows: bank-floor)
  __shared__ __align__(16) short Bs[2][4096];
  __shared__ unsigned rowprov[128];
  __shared__ unsigned rowcnt[128];
  __shared__ unsigned short rowcand[128][CAP];

  const int tid = threadIdx.x;
  const int l = tid & 63, v = tid >> 6;
  const int n0 = blockIdx.x * 128;
  const int qr = v >> 1, qc = v & 1;            // wave tile: rows 32*qr, cols 64*qc

  if (tid < 128) { rowprov[tid] = 0x7F800000u; rowcnt[tid] = 0u; }

  float xv[2][4];
  #pragma unroll
  for (int m = 0; m < 2; ++m)
    #pragma unroll
    for (int r = 0; r < 4; ++r)
      xv[m][r] = xx[n0 + qr * 32 + m * 16 + (l >> 4) * 4 + r];

  const int srcrow = tid >> 2, srcoff = (tid & 3) * 16;

  // stage u: k0 = (u>>3)*128, d0 = (u&7)*32
  #define STAGE(buf, u) do {                                                   \
    int k0_ = ((u) >> 3) * 128, d0_ = ((u) & 7) * 32;                          \
    gload16((const char*)x2 + (size_t)(n0 + srcrow) * 512 + d0_ * 2 + srcoff,  \
            (char*)As[buf] + v * 1024);                                        \
    gload16((const char*)w2 + (size_t)(k0_ + srcrow) * 512 + d0_ * 2 + srcoff, \
            (char*)Bs[buf] + v * 1024);                                        \
  } while (0)

  f32x4 acc[2][4];
  int cur = 0;
  STAGE(0, 0);
  __syncthreads();

  for (int u = 0; u < 64; ++u) {
    if ((u & 7) == 0) {
      #pragma unroll
      for (int m = 0; m < 2; ++m)
        #pragma unroll
        for (int n = 0; n < 4; ++n) acc[m][n] = (f32x4){0.f, 0.f, 0.f, 0.f};
    }
    if (u < 63) STAGE(cur ^ 1, u + 1);

    short8 af[2], bfr[4];
    #pragma unroll
    for (int m = 0; m < 2; ++m)
      af[m] = *(const short8*)((const char*)As[cur] +
                               (qr * 32 + m * 16 + (l & 15)) * 64 + (l >> 4) * 16);
    #pragma unroll
    for (int n = 0; n < 4; ++n)
      bfr[n] = *(const short8*)((const char*)Bs[cur] +
                                (qc * 64 + n * 16 + (l & 15)) * 64 + (l >> 4) * 16);
    #pragma unroll
    for (int m = 0; m < 2; ++m)
      #pragma unroll
      for (int n = 0; n < 4; ++n)
        asm("v_mfma_f32_16x16x32_f16 %0, %1, %2, %0"
            : "+v"(acc[m][n]) : "v"(af[m]), "v"(bfr[n]));

    if ((u & 7) == 7) {                 // k0-chunk complete: dist + shortlist
      const int k0 = (u >> 3) * 128;
      float wv[4];
      float rmin[2][4];
      #pragma unroll
      for (int m = 0; m < 2; ++m)
        #pragma unroll
        for (int r = 0; r < 4; ++r) rmin[m][r] = 3.4e38f;
      #pragma unroll
      for (int n = 0; n < 4; ++n) {
        const int kg = k0 + qc * 64 + n * 16 + (l & 15);
        wv[n] = ww[kg];
        #pragma unroll
        for (int m = 0; m < 2; ++m)
          #pragma unroll
          for (int r = 0; r < 4; ++r) {
            const int rl = qr * 32 + m * 16 + (l >> 4) * 4 + r;
            float dd = (xv[m][r] - acc[m][n][r] * (1.f / 512.f)) + wv[n];
            dist[(size_t)(n0 + rl) * 1024 + kg] = dd;
            rmin[m][r] = fminf(rmin[m][r], dd);
          }
      }
      #pragma unroll
      for (int off = 1; off < 16; off <<= 1)
        #pragma unroll
        for (int m = 0; m < 2; ++m)
          #pragma unroll
          for (int r = 0; r < 4; ++r)
            rmin[m][r] = fminf(rmin[m][r], __shfl_xor(rmin[m][r], off));
      if ((l & 15) == 0) {
        #pragma unroll
        for (int m = 0; m < 2; ++m)
          #pragma unroll
          for (int r = 0; r < 4; ++r)
            atomicMin(&rowprov[qr * 32 + m * 16 + (l >> 4) * 4 + r],
                      __float_as_uint(rmin[m][r]));
      }
      __syncthreads();
      #pragma unroll
      for (int n = 0; n < 4; ++n) {
        const int kg = k0 + qc * 64 + n * 16 + (l & 15);
        #pragma unroll
        for (int m = 0; m < 2; ++m)
          #pragma unroll
          for (int r = 0; r < 4; ++r) {
            const int rl = qr * 32 + m * 16 + (l >> 4) * 4 + r;
            float dd = (xv[m][r] - acc[m][n][r] * (1.f / 512.f)) + wv[n];
            if (dd < __uint_as_float(rowprov[rl]) + MARGIN) {
              unsigned slot = atomicAdd(&rowcnt[rl], 1u);
              if (slot < CAP) rowcand[rl][slot] = (unsigned short)kg;
            }
          }
      }
    }
    __syncthreads();
    cur ^= 1;
  }

  if (tid < 128) {
    unsigned c = rowcnt[tid];
    unsigned short* dst = cand + (size_t)(n0 + tid) * 16;
    dst[0] = (c > CAP) ? (unsigned short)0xFFFF : (unsigned short)c;
    #pragma unroll
    for (int i = 0; i < CAP; ++i) dst[1 + i] = rowcand[tid][i];
  }
  #undef STAGE
}

// ---- exact re-eval of shortlist: round-1 arithmetic (seq fmaf + np op seq)
__global__ __launch_bounds__(256) void k_reeval(const float* __restrict__ in,
                                                const float* __restrict__ w,
                                                const float* __restrict__ xx,
                                                const float* __restrict__ ww,
                                                const unsigned short* __restrict__ cand,
                                                int* __restrict__ aidx) {
  int n = blockIdx.x * 256 + threadIdx.x;
  int b = n >> 10, hw = n & 1023;
  const unsigned short* c = cand + (size_t)n * 16;
  int cnt = c[0];
  int best;
  if (cnt == 1) {
    best = c[1];
  } else {
    const float* xp = in + (size_t)b * CHW + hw;
    const float xxv = xx[n];
    float bd = 3.4e38f; int bk = 1 << 30;
    const bool full = (cnt > CAP);
    const int m = full ? K_EMB : cnt;
    for (int i = 0; i < m; ++i) {
      int k = full ? i : (int)c[1 + i];
      const float* wr = w + (size_t)k * D_EMB;
      float acc = 0.f;
      for (int d = 0; d < D_EMB; ++d)
        acc = fmaf(xp[(size_t)d * HW], wr[d], acc);   // sequential k-chain (BLAS order)
      float t = 2.0f * acc;
      asm volatile("" : "+v"(t));                     // np: 2.0*M as separate op
      float s = xxv - t;
      asm volatile("" : "+v"(s));                     // np: (sum - t) before + ww
      float dd = s + ww[k];
      if (dd < bd || (dd == bd && k < bk)) { bd = dd; bk = k; }
    }
    best = bk;
  }
  aidx[n] = best;
}

// ---- epilogue: quantized/STE, one-hot enc, idx, loss, histogram -----------
__global__ __launch_bounds__(256) void k_epi2(const float* __restrict__ in,
                                              const float* __restrict__ w,
                                              const int* __restrict__ aidx,
                                              float* __restrict__ outq,
                                              float* __restrict__ enc,
                                              float* __restrict__ idxf,
                                              int* __restrict__ cnt,
                                              double* __restrict__ lossp) {
  __shared__ double sred[256];
  __shared__ int sidx[64];
  const int tid = threadIdx.x;
  const int rr = tid & 63, qd = tid >> 6;
  const int n0 = blockIdx.x * 64;
  const int n = n0 + rr;
  const int b = n >> 10, hw = n & 1023;
  if (qd == 0) sidx[rr] = aidx[n];
  __syncthreads();
  const int idx = sidx[rr];
  const float* xp = in + (size_t)b * CHW + hw;
  float* qp = outq + (size_t)b * CHW + hw;
  const float* wrow = w + (size_t)idx * D_EMB;
  double ls = 0.0;
  for (int j = 0; j < 64; ++j) {
    int d = qd * 64 + j;
    float xvv = xp[(size_t)d * HW];
    float q = wrow[d];
    float t = q - xvv;                 // fl(q-x) as np
    qp[(size_t)d * HW] = xvv + t;      // STE bit-identical
    ls += (double)(t * t);
  }
  if (qd == 0) { idxf[n] = (float)idx; atomicAdd(&cnt[idx], 1); }
  // one-hot rows (also the zero-fill; replaces 256MB memset)
  for (int it = 0; it < 64; ++it) {
    int ii = sidx[it];
    f32x4 z = {0.f, 0.f, 0.f, 0.f};
    if ((ii >> 2) == tid) z[ii & 3] = 1.f;
    *(f32x4u*)&enc[(size_t)(n0 + it) * 1024 + tid * 4] = z;
  }
  sred[tid] = ls; __syncthreads();
  for (int s = 128; s > 0; s >>= 1) {
    if (tid < s) sred[tid] += sred[tid + s];
    __syncthreads();
  }
  if (tid == 0) lossp[blockIdx.x] = sred[0];
}

// ---- finalize scalars -----------------------------------------------------
__global__ __launch_bounds__(256) void k_final(const double* __restrict__ lossp,
                                               const int* __restrict__ cnt,
                                               float* __restrict__ out_loss,
                                               float* __restrict__ out_ppl) {
  __shared__ double sred[256];
  int t = threadIdx.x;
  sred[t] = lossp[t] + lossp[t + 256] + lossp[t + 512] + lossp[t + 768];
  __syncthreads();
  for (int s = 128; s > 0; s >>= 1) {
    if (t < s) sred[t] += sred[t + s];
    __syncthreads();
  }
  if (t == 0) *out_loss = (float)(1.25 * (sred[0] / 16777216.0));
  __syncthreads();
  double es = 0.0;
  for (int k = t; k < K_EMB; k += 256) {
    float p = (float)cnt[k] * (1.0f / 65536.0f);
    float term = p * logf(p + 1e-10f);
    es += (double)term;
  }
  sred[t] = es;
  __syncthreads();
  for (int s = 128; s > 0; s >>= 1) {
    if (t < s) sred[t] += sred[t + s];
    __syncthreads();
  }
  if (t == 0) *out_ppl = expf((float)(-sred[0]));
}

extern "C" void kernel_launch(void* const* d_in, const int* in_sizes, int n_in,
                              void* d_out, int out_size, void* d_ws, size_t ws_size,
                              hipStream_t stream) {
  const float* in = (const float*)d_in[0];
  const float* w  = (const float*)d_in[1];
  float* out = (float*)d_out;
  char* ws = (char*)d_ws;

  int*    cnt   = (int*)(ws + WS_CNT);
  double* lossp = (double*)(ws + WS_LOSSP);
  float*  xx    = (float*)(ws + WS_XX);
  float*  wwp   = (float*)(ws + WS_WW);
  int*    aidx  = (int*)(ws + WS_AIDX);

  // scratch in the enc output region (overwritten only later by k_epi2).
  // +3 floats past O_ENC -> 16B-aligned base.
  unsigned short* x2   = (unsigned short*)(out + O_ENC + 3);  // f16 [65536][256]
  unsigned short* w2   = x2 + (size_t)N_TOT * 256;            // f16 [1024][256]
  unsigned short* cand = w2 + (size_t)K_EMB * 256;            // u16 [65536][16]

  hipMemsetAsync(cnt, 0, 4096, stream);

  k_prep_x<<<256, 256, 0, stream>>>(in, x2, xx);
  k_prep_w<<<4, 256, 0, stream>>>(w, w2, wwp);
  k_coarse<<<512, 512, 0, stream>>>(x2, w2, xx, wwp, out + O_DIST, cand);
  k_reeval<<<256, 256, 0, stream>>>(in, w, xx, wwp, cand, aidx);
  k_epi2<<<1024, 256, 0, stream>>>(in, w, aidx, out + O_Q, out + O_ENC,
                                   out + O_IDX, cnt, lossp);
  k_final<<<1, 256, 0, stream>>>(lossp, cnt, out + O_LOSS, out + O_PPL);
}

// Round 10
// 1020.119 us; speedup vs baseline: 1.1765x; 1.0067x over previous
//
#include <hip/hip_runtime.h>
#include <hip/hip_fp16.h>

#define N_TOT   65536
#define K_EMB   1024
#define D_EMB   256
#define HW      1024
#define CHW     (D_EMB * HW)

// output offsets (float elements), reference tuple order
#define O_DIST  0
#define O_Q     67108864
#define O_LOSS  83886080
#define O_ENC   83886081
#define O_IDX   150994945
#define O_PPL   151060481

// workspace offsets (bytes)
#define WS_CNT   0                     // int[1024]
#define WS_LOSSP 4096                  // double[2048] -> 20480
#define WS_XX    20480                 // float[65536] -> 282624
#define WS_WW    282624                // float[1024]  -> 286720
#define WS_AIDX  286720                // int[65536]   -> 548864

#define CAP     15
#define MARGIN  3.0e-4f

typedef float  f32x4  __attribute__((ext_vector_type(4)));
typedef short  short8 __attribute__((ext_vector_type(8)));
typedef unsigned short ushort8 __attribute__((ext_vector_type(8)));
typedef f32x4 __attribute__((aligned(4))) f32x4u;

// LDS slot swizzle for 64B-row tiles: 2-bit slot XOR keyed by row -> 2-way max
#define SWZ(row) ((((row) & 3) ^ (((row) >> 2) & 1)) << 4)

static __device__ __forceinline__ void gload16(const void* g, void* l) {
  __builtin_amdgcn_global_load_lds(
      (const __attribute__((address_space(1))) unsigned int*)g,
      (__attribute__((address_space(3))) unsigned int*)l, 16, 0, 0);
}

// ---- prep x: f16 convert + numpy-pairwise-exact ||x||^2 -------------------
__global__ __launch_bounds__(256) void k_prep_x(const float* __restrict__ in,
                                                unsigned short* __restrict__ x2,
                                                float* __restrict__ xx) {
  int n = blockIdx.x * 256 + threadIdx.x;
  int b = n >> 10, hw = n & 1023;
  const float* p = in + (size_t)b * CHW + hw;
  float hsum[2];
  #pragma unroll
  for (int half = 0; half < 2; ++half) {
    float r[8];
    for (int i = 0; i < 128; i += 8) {
      ushort8 hv;
      #pragma unroll
      for (int j = 0; j < 8; ++j) {
        int d = half * 128 + i + j;
        float v = p[(size_t)d * HW];
        float sq = v * v;
        asm volatile("" : "+v"(sq));      // np rounds v*v before summing
        if (i == 0) r[j] = sq; else r[j] += sq;
        hv[j] = __half_as_ushort(__float2half_rn(v));
      }
      *(ushort8*)&x2[(size_t)n * 256 + half * 128 + i] = hv;
    }
    hsum[half] = ((r[0] + r[1]) + (r[2] + r[3])) + ((r[4] + r[5]) + (r[6] + r[7]));
  }
  xx[n] = hsum[0] + hsum[1];
}

// ---- prep w: f16(1024*w) + numpy-pairwise-exact ||w||^2 -------------------
__global__ __launch_bounds__(256) void k_prep_w(const float* __restrict__ w,
                                                unsigned short* __restrict__ w2,
                                                float* __restrict__ ww) {
  int k = blockIdx.x * 256 + threadIdx.x;
  const float* p = w + (size_t)k * D_EMB;
  float hsum[2];
  #pragma unroll
  for (int half = 0; half < 2; ++half) {
    float r[8];
    for (int i = 0; i < 128; i += 8) {
      ushort8 hv;
      #pragma unroll
      for (int j = 0; j < 8; ++j) {
        float v = p[half * 128 + i + j];
        float sq = v * v;
        asm volatile("" : "+v"(sq));
        if (i == 0) r[j] = sq; else r[j] += sq;
        hv[j] = __half_as_ushort(__float2half_rn(v * 1024.f));  // exact scale
      }
      *(ushort8*)&w2[(size_t)k * 256 + half * 128 + i] = hv;
    }
    hsum[half] = ((r[0] + r[1]) + (r[2] + r[3])) + ((r[4] + r[5]) + (r[6] + r[7]));
  }
  ww[k] = hsum[0] + hsum[1];
}

// ---- coarse MFMA GEMM: dist output + per-row candidate shortlist ----------
// 512 blocks x 512 thr; block owns 128 rows x ALL 1024 cols. BK=32 dbuf.
// LDS tiles slot-swizzled (SWZ) on both write-source and read: 2-way max.
__global__ __launch_bounds__(512) void k_coarse(const unsigned short* __restrict__ x2,
                                                const unsigned short* __restrict__ w2,
                                                const float* __restrict__ xx,
                                                const float* __restrict__ ww,
                                                float* __restrict__ dist,
                                                unsigned short* __restrict__ cand) {
  __shared__ __align__(16) short As[2][4096];   // [128][32] f16, swizzled slots
  __shared__ __align__(16) short Bs[2][4096];
  __shared__ unsigned rowprov[128];
  __shared__ unsigned rowcnt[128];
  __shared__ unsigned short rowcand[128][CAP];

  const int tid = threadIdx.x;
  const int l = tid & 63, v = tid >> 6;
  const int n0 = blockIdx.x * 128;
  const int qr = v >> 1, qc = v & 1;            // wave tile: rows 32*qr, cols 64*qc

  if (tid < 128) { rowprov[tid] = 0x7F800000u; rowcnt[tid] = 0u; }

  float xv[2][4];
  #pragma unroll
  for (int m = 0; m < 2; ++m)
    #pragma unroll
    for (int r = 0; r < 4; ++r)
      xv[m][r] = xx[n0 + qr * 32 + m * 16 + (l >> 4) * 4 + r];

  const int srcrow = tid >> 2;
  const int srcoff = ((tid & 3) * 16) ^ SWZ(srcrow);   // pre-swizzled source slot

  // stage u: k0 = (u>>3)*128, d0 = (u&7)*32
  #define STAGE(buf, u) do {                                                   \
    int k0_ = ((u) >> 3) * 128, d0_ = ((u) & 7) * 32;                          \
    gload16((const char*)x2 + (size_t)(n0 + srcrow) * 512 + d0_ * 2 + srcoff,  \
            (char*)As[buf] + v * 1024);                                        \
    gload16((const char*)w2 + (size_t)(k0_ + srcrow) * 512 + d0_ * 2 + srcoff, \
            (char*)Bs[buf] + v * 1024);                                        \
  } while (0)

  f32x4 acc[2][4];
  int cur = 0;
  STAGE(0, 0);
  __syncthreads();

  for (int u = 0; u < 64; ++u) {
    if ((u & 7) == 0) {
      #pragma unroll
      for (int m = 0; m < 2; ++m)
        #pragma unroll
        for (int n = 0; n < 4; ++n) acc[m][n] = (f32x4){0.f, 0.f, 0.f, 0.f};
    }
    if (u < 63) STAGE(cur ^ 1, u + 1);

    short8 af[2], bfr[4];
    #pragma unroll
    for (int m = 0; m < 2; ++m) {
      int row = qr * 32 + m * 16 + (l & 15);
      af[m] = *(const short8*)((const char*)As[cur] +
                               row * 64 + (((l >> 4) * 16) ^ SWZ(row)));
    }
    #pragma unroll
    for (int n = 0; n < 4; ++n) {
      int row = qc * 64 + n * 16 + (l & 15);
      bfr[n] = *(const short8*)((const char*)Bs[cur] +
                                row * 64 + (((l >> 4) * 16) ^ SWZ(row)));
    }
    #pragma unroll
    for (int m = 0; m < 2; ++m)
      #pragma unroll
      for (int n = 0; n < 4; ++n)
        asm("v_mfma_f32_16x16x32_f16 %0, %1, %2, %0"
            : "+v"(acc[m][n]) : "v"(af[m]), "v"(bfr[n]));

    if ((u & 7) == 7) {                 // k0-chunk complete: dist + shortlist
      const int k0 = (u >> 3) * 128;
      float wv[4];
      float rmin[2][4];
      #pragma unroll
      for (int m = 0; m < 2; ++m)
        #pragma unroll
        for (int r = 0; r < 4; ++r) rmin[m][r] = 3.4e38f;
      #pragma unroll
      for (int n = 0; n < 4; ++n) {
        const int kg = k0 + qc * 64 + n * 16 + (l & 15);
        wv[n] = ww[kg];
        #pragma unroll
        for (int m = 0; m < 2; ++m)
          #pragma unroll
          for (int r = 0; r < 4; ++r) {
            const int rl = qr * 32 + m * 16 + (l >> 4) * 4 + r;
            float dd = (xv[m][r] - acc[m][n][r] * (1.f / 512.f)) + wv[n];
            dist[(size_t)(n0 + rl) * 1024 + kg] = dd;
            rmin[m][r] = fminf(rmin[m][r], dd);
          }
      }
      #pragma unroll
      for (int off = 1; off < 16; off <<= 1)
        #pragma unroll
        for (int m = 0; m < 2; ++m)
          #pragma unroll
          for (int r = 0; r < 4; ++r)
            rmin[m][r] = fminf(rmin[m][r], __shfl_xor(rmin[m][r], off));
      if ((l & 15) == 0) {
        #pragma unroll
        for (int m = 0; m < 2; ++m)
          #pragma unroll
          for (int r = 0; r < 4; ++r)
            atomicMin(&rowprov[qr * 32 + m * 16 + (l >> 4) * 4 + r],
                      __float_as_uint(rmin[m][r]));
      }
      __syncthreads();
      #pragma unroll
      for (int n = 0; n < 4; ++n) {
        const int kg = k0 + qc * 64 + n * 16 + (l & 15);
        #pragma unroll
        for (int m = 0; m < 2; ++m)
          #pragma unroll
          for (int r = 0; r < 4; ++r) {
            const int rl = qr * 32 + m * 16 + (l >> 4) * 4 + r;
            float dd = (xv[m][r] - acc[m][n][r] * (1.f / 512.f)) + wv[n];
            if (dd < __uint_as_float(rowprov[rl]) + MARGIN) {
              unsigned slot = atomicAdd(&rowcnt[rl], 1u);
              if (slot < CAP) rowcand[rl][slot] = (unsigned short)kg;
            }
          }
      }
    }
    __syncthreads();
    cur ^= 1;
  }

  if (tid < 128) {
    unsigned c = rowcnt[tid];
    unsigned short* dst = cand + (size_t)(n0 + tid) * 16;
    dst[0] = (c > CAP) ? (unsigned short)0xFFFF : (unsigned short)c;
    #pragma unroll
    for (int i = 0; i < CAP; ++i) dst[1 + i] = rowcand[tid][i];
  }
  #undef STAGE
}

// ---- exact re-eval of shortlist + idx outputs + histogram -----------------
__global__ __launch_bounds__(256) void k_reeval(const float* __restrict__ in,
                                                const float* __restrict__ w,
                                                const float* __restrict__ xx,
                                                const float* __restrict__ ww,
                                                const unsigned short* __restrict__ cand,
                                                int* __restrict__ aidx,
                                                float* __restrict__ idxf,
                                                int* __restrict__ cnt) {
  int n = blockIdx.x * 256 + threadIdx.x;
  int b = n >> 10, hw = n & 1023;
  const unsigned short* c = cand + (size_t)n * 16;
  int cc = c[0];
  int best;
  if (cc == 1) {
    best = c[1];
  } else {
    const float* xp = in + (size_t)b * CHW + hw;
    const float xxv = xx[n];
    float bd = 3.4e38f; int bk = 1 << 30;
    const bool full = (cc > CAP);
    const int m = full ? K_EMB : cc;
    for (int i = 0; i < m; ++i) {
      int k = full ? i : (int)c[1 + i];
      const float* wr = w + (size_t)k * D_EMB;
      float acc = 0.f;
      for (int d = 0; d < D_EMB; ++d)
        acc = fmaf(xp[(size_t)d * HW], wr[d], acc);   // sequential k-chain (BLAS order)
      float t = 2.0f * acc;
      asm volatile("" : "+v"(t));                     // np: 2.0*M as separate op
      float s = xxv - t;
      asm volatile("" : "+v"(s));                     // np: (sum - t) before + ww
      float dd = s + ww[k];
      if (dd < bd || (dd == bd && k < bk)) { bd = dd; bk = k; }
    }
    best = bk;
  }
  aidx[n] = best;
  idxf[n] = (float)best;
  atomicAdd(&cnt[best], 1);
}

// ---- quantized/STE + loss: (b, 8-d-group) blocks, float4 in/out -----------
// grid 2048 = 64 b x 32 dg; LDS w_sub[1024][9] (stride-9 -> conflict-free gather)
__global__ __launch_bounds__(256) void k_epi2(const float* __restrict__ in,
                                              const float* __restrict__ w,
                                              const int* __restrict__ aidx,
                                              float* __restrict__ outq,
                                              double* __restrict__ lossp) {
  __shared__ float wsub[1024 * 9];
  __shared__ int sidx[1024];
  __shared__ double sred[256];
  const int tid = threadIdx.x;
  const int b = blockIdx.x >> 5, dg = blockIdx.x & 31;
  const int d0 = dg * 8;
  // stage w sub-columns [k][8]
  for (int it = 0; it < 32; ++it) {
    int kk = it * 32 + (tid >> 3);
    int cc = tid & 7;
    wsub[kk * 9 + cc] = w[(size_t)kk * D_EMB + d0 + cc];
  }
  { f32x4 z;  // reuse f32x4 as int4 carrier via reinterpret
    const int4 iv = *(const int4*)&aidx[b * 1024 + tid * 4];
    sidx[tid * 4 + 0] = iv.x; sidx[tid * 4 + 1] = iv.y;
    sidx[tid * 4 + 2] = iv.z; sidx[tid * 4 + 3] = iv.w; (void)z; }
  __syncthreads();
  const int hw4 = tid * 4;
  const int i0 = sidx[hw4], i1 = sidx[hw4 + 1], i2 = sidx[hw4 + 2], i3 = sidx[hw4 + 3];
  const float* ip = in + (size_t)b * CHW + hw4;
  float* qp = outq + (size_t)b * CHW + hw4;
  double ls = 0.0;
  #pragma unroll
  for (int dd = 0; dd < 8; ++dd) {
    const int d = d0 + dd;
    float4 xv = *(const float4*)&ip[(size_t)d * HW];
    float q0 = wsub[i0 * 9 + dd], q1 = wsub[i1 * 9 + dd];
    float q2 = wsub[i2 * 9 + dd], q3 = wsub[i3 * 9 + dd];
    float t0 = q0 - xv.x, t1 = q1 - xv.y, t2 = q2 - xv.z, t3 = q3 - xv.w;
    float4 o;                              // STE: fl(x + fl(q-x)) as np
    o.x = xv.x + t0; o.y = xv.y + t1; o.z = xv.z + t2; o.w = xv.w + t3;
    *(float4*)&qp[(size_t)d * HW] = o;
    ls += (double)(t0 * t0) + (double)(t1 * t1)
        + (double)(t2 * t2) + (double)(t3 * t3);
  }
  sred[tid] = ls; __syncthreads();
  for (int s = 128; s > 0; s >>= 1) {
    if (tid < s) sred[tid] += sred[tid + s];
    __syncthreads();
  }
  if (tid == 0) lossp[blockIdx.x] = sred[0];
}

// ---- one-hot encodings (also the zero-fill; overwrites scratch region) ----
__global__ __launch_bounds__(256) void k_enc(const int* __restrict__ aidx,
                                             float* __restrict__ enc) {
  __shared__ int sidx[64];
  const int tid = threadIdx.x;
  const int n0 = blockIdx.x * 64;
  if (tid < 64) sidx[tid] = aidx[n0 + tid];
  __syncthreads();
  for (int it = 0; it < 64; ++it) {
    int ii = sidx[it];
    f32x4 z = {0.f, 0.f, 0.f, 0.f};
    if ((ii >> 2) == tid) z[ii & 3] = 1.f;
    *(f32x4u*)&enc[(size_t)(n0 + it) * 1024 + tid * 4] = z;
  }
}

// ---- finalize scalars -----------------------------------------------------
__global__ __launch_bounds__(256) void k_final(const double* __restrict__ lossp,
                                               const int* __restrict__ cnt,
                                               float* __restrict__ out_loss,
                                               float* __restrict__ out_ppl) {
  __shared__ double sred[256];
  int t = threadIdx.x;
  double a = 0.0;
  #pragma unroll
  for (int i = 0; i < 8; ++i) a += lossp[t + 256 * i];
  sred[t] = a;
  __syncthreads();
  for (int s = 128; s > 0; s >>= 1) {
    if (t < s) sred[t] += sred[t + s];
    __syncthreads();
  }
  if (t == 0) *out_loss = (float)(1.25 * (sred[0] / 16777216.0));
  __syncthreads();
  double es = 0.0;
  for (int k = t; k < K_EMB; k += 256) {
    float p = (float)cnt[k] * (1.0f / 65536.0f);
    float term = p * logf(p + 1e-10f);
    es += (double)term;
  }
  sred[t] = es;
  __syncthreads();
  for (int s = 128; s > 0; s >>= 1) {
    if (t < s) sred[t] += sred[t + s];
    __syncthreads();
  }
  if (t == 0) *out_ppl = expf((float)(-sred[0]));
}

extern "C" void kernel_launch(void* const* d_in, const int* in_sizes, int n_in,
                              void* d_out, int out_size, void* d_ws, size_t ws_size,
                              hipStream_t stream) {
  const float* in = (const float*)d_in[0];
  const float* w  = (const float*)d_in[1];
  float* out = (float*)d_out;
  char* ws = (char*)d_ws;

  int*    cnt   = (int*)(ws + WS_CNT);
  double* lossp = (double*)(ws + WS_LOSSP);
  float*  xx    = (float*)(ws + WS_XX);
  float*  wwp   = (float*)(ws + WS_WW);
  int*    aidx  = (int*)(ws + WS_AIDX);

  // scratch in the enc output region (k_enc overwrites it at the end).
  // +3 floats past O_ENC -> 16B-aligned base.
  unsigned short* x2   = (unsigned short*)(out + O_ENC + 3);  // f16 [65536][256]
  unsigned short* w2   = x2 + (size_t)N_TOT * 256;            // f16 [1024][256]
  unsigned short* cand = w2 + (size_t)K_EMB * 256;            // u16 [65536][16]

  hipMemsetAsync(cnt, 0, 4096, stream);

  k_prep_x<<<256, 256, 0, stream>>>(in, x2, xx);
  k_prep_w<<<4, 256, 0, stream>>>(w, w2, wwp);
  k_coarse<<<512, 512, 0, stream>>>(x2, w2, xx, wwp, out + O_DIST, cand);
  k_reeval<<<256, 256, 0, stream>>>(in, w, xx, wwp, cand, aidx,
                                    out + O_IDX, cnt);
  k_epi2<<<2048, 256, 0, stream>>>(in, w, aidx, out + O_Q, lossp);
  k_enc<<<1024, 256, 0, stream>>>(aidx, out + O_ENC);
  k_final<<<1, 256, 0, stream>>>(lossp, cnt, out + O_LOSS, out + O_PPL);
}